// Round 6
// baseline (4762.049 us; speedup 1.0000x reference)
//
#include <hip/hip_runtime.h>
#include <stdint.h>

#define NB 16
#define WIN 168
#define NSTEPS 24
#define NBLK (4096/NB)
#define NT 512

typedef __attribute__((ext_vector_type(8))) short bf16x8;
typedef __attribute__((ext_vector_type(4))) float f32x4;
typedef __attribute__((ext_vector_type(2))) float f32x2;

#if __has_builtin(__builtin_amdgcn_rcpf)
#define RCPF(x) __builtin_amdgcn_rcpf(x)
#else
#define RCPF(x) (1.0f / (x))
#endif
#if __has_builtin(__builtin_amdgcn_exp2f)
#define EXP2F(x) __builtin_amdgcn_exp2f(x)
#else
#define EXP2F(x) __expf((x) * 0.6931471805599453f)
#endif

__device__ __forceinline__ float sigm(float x){
  return RCPF(1.0f + EXP2F(x * -1.4426950408889634f));
}
__device__ __forceinline__ float sigtanh(float a, float b){
  float A = EXP2F(a * -1.4426950408889634f);
  float B = EXP2F(fabsf(b) * -2.8853900817779268f);
  float t = (1.0f - B) * RCPF((1.0f + A) * (1.0f + B));
  return __builtin_copysignf(t, b);   // t >= 0 always
}

// ---- packed-f32 helpers (R17): full-rate ops 2-wide, trans stay scalar. Bit-identical.
__device__ __forceinline__ f32x2 exp2v(f32x2 x){ return (f32x2){EXP2F(x.x), EXP2F(x.y)}; }
__device__ __forceinline__ f32x2 rcpv(f32x2 x){ return (f32x2){RCPF(x.x), RCPF(x.y)}; }
__device__ __forceinline__ f32x2 absv(f32x2 x){ return (f32x2){fabsf(x.x), fabsf(x.y)}; }
__device__ __forceinline__ f32x2 csignv(f32x2 t, f32x2 s){
  return (f32x2){__builtin_copysignf(t.x, s.x), __builtin_copysignf(t.y, s.y)};
}
__device__ __forceinline__ f32x2 sigmv(f32x2 x){
  return rcpv(1.0f + exp2v(x * -1.4426950408889634f));
}
__device__ __forceinline__ f32x2 sigtanhv(f32x2 a, f32x2 b){
  f32x2 A = exp2v(a * -1.4426950408889634f);
  f32x2 B = exp2v(absv(b) * -2.8853900817779268f);
  f32x2 t = (1.0f - B) * rcpv((1.0f + A) * (1.0f + B));
  return csignv(t, b);
}

__device__ __forceinline__ uint32_t bf_rn(float f){
  uint32_t u = __builtin_bit_cast(uint32_t, f);
  return (u + 0x7FFFu + ((u >> 16) & 1u)) >> 16;
}
__device__ __forceinline__ float bf_f(uint32_t s){
  return __builtin_bit_cast(float, s << 16);
}
__device__ __forceinline__ void split_t(float f, uint32_t& hi, uint32_t& lo){
  uint32_t u = __builtin_bit_cast(uint32_t, f);
  hi = u >> 16;
  lo = bf_rn(f - bf_f(hi));
}
__device__ __forceinline__ void split_s(float f, short& hi, short& lo){
  uint32_t h = bf_rn(f);
  hi = (short)h;
  lo = (short)bf_rn(f - bf_f(h));
}
__device__ __forceinline__ uint32_t cvtpk2(float a, float b){
  uint32_t r;
  asm("v_cvt_pk_bf16_f32 %0, %1, %2" : "=v"(r) : "v"(a), "v"(b));
  return r;
}
__device__ __forceinline__ float hi_even(uint32_t p){
  return __builtin_bit_cast(float, p << 16);
}
__device__ __forceinline__ float hi_odd(uint32_t p){
  return __builtin_bit_cast(float, p & 0xFFFF0000u);
}
__device__ __forceinline__ f32x4 mfma16(bf16x8 a, bf16x8 b, f32x4 c){
  return __builtin_amdgcn_mfma_f32_16x16x32_bf16(a, b, c, 0, 0, 0);
}

// R17 packed epilogue. Bit-identical to scalar form.
__device__ __forceinline__ void lstm_epi(const f32x4 acc[4], float c[4], float hn[4]){
  #pragma unroll
  for (int p = 0; p < 2; p++){
    const int r0 = 2*p;
    f32x2 gi = {acc[0][r0], acc[0][r0+1]};
    f32x2 gf = {acc[1][r0], acc[1][r0+1]};
    f32x2 gg = {acc[2][r0], acc[2][r0+1]};
    f32x2 go = {acc[3][r0], acc[3][r0+1]};
    f32x2 cc = {c[r0], c[r0+1]};
    f32x2 cn = __builtin_elementwise_fma(sigmv(gf), cc, sigtanhv(gi, gg));
    f32x2 hh = sigtanhv(go, cn);
    c[r0] = cn.x; c[r0+1] = cn.y;
    hn[r0] = hh.x; hn[r0+1] = hh.y;
  }
}

#define FROW 136
#define FBLK 544
#define FB(buf,hl,kt) ((((buf)*2 + (hl))*2 + (kt)) * FBLK)
#define BUF_INTS (2*FBLK)

// ---- agent-scope flag sync (cross-XCD safe per G16) ----
__device__ __forceinline__ void flag_set(uint32_t* f){
  __threadfence();
  __hip_atomic_store(f, 1u, __ATOMIC_RELEASE, __HIP_MEMORY_SCOPE_AGENT);
}
__device__ __forceinline__ void flag_wait(uint32_t* f){
  while (__hip_atomic_load(f, __ATOMIC_ACQUIRE, __HIP_MEMORY_SCOPE_AGENT) == 0u)
    __builtin_amdgcn_s_sleep(2);
}

// ============================================================================
// R18: decoupled producer/consumer WORKGROUPS. Evidence: R17 cut VALU issue
// (VALUBusy 61->54) with only -1.5% time => limiter is the lockstep coupling
// of A and B waves at 4247 block-wide barriers (phase collision on the shared
// trans unit / MFMA pipe + 8-wave convergence), NOT issue count. A and B have
// ZERO per-interval data deps on each other; the hist-ring anti-dependency is
// removed with a 2-sweep hist double-buffer. So: 512 blocks of 256 threads,
// pairs (A_b = blockIdx 2b, B_b = 2b+1). A(sg+1) runs concurrently with B(sg);
// sweep-level sync via agent-scope flags (24/block). The flagFC poll at A's
// t=167 provably fences 2-sweep hist buffer reuse (A(sg+2) starts only after
// B(sg) done). Pairs are self-contained => deadlock-free for any schedule.
// Barriers are now 4-wave role-local; phases drift => trans/MFMA interleave.
// Math, accumulation order, layouts identical => absmax bit-identical.
// Workspace: 2x hist (336MB) + handoffs + flags; gated, R17 kernel kept as
// the proven fallback when ws is too small.
// ============================================================================
__global__ void flags_zero_kernel(uint32_t* flags, int n){
  int i = blockIdx.x*blockDim.x + threadIdx.x;
  if (i < n) flags[i] = 0u;
}

__global__ __launch_bounds__(256, 2) void lstm_pipe_kernel(
  const float* __restrict__ x,    const float* __restrict__ Wih1, const float* __restrict__ Whh1,
  const float* __restrict__ bih1, const float* __restrict__ bhh1,
  const float* __restrict__ Wih2, const float* __restrict__ Whh2,
  const float* __restrict__ bih2, const float* __restrict__ bhh2,
  const float* __restrict__ fc1w, const float* __restrict__ fc1b,
  const float* __restrict__ fc2w, const float* __restrict__ fc2b,
  float* __restrict__ out, short* __restrict__ hist,
  short* __restrict__ hoff, float* __restrict__ cg, uint32_t* __restrict__ flags)
{
  __shared__ __align__(16) short aS[2*2*2*FBLK];   // A: LSTM1 state dbuf
  __shared__ __align__(16) short bS[2*2*2*FBLK];   // B: LSTM2 state dbuf
  __shared__ float win_s[WIN][NB];                 // A: original x window
  __shared__ float Hlast[NB][68];                  // B
  __shared__ float fc1w_s[64*68];                  // B
  __shared__ float dval_s[NB];                     // B

  const int b   = blockIdx.x >> 1;
  const bool isA = ((blockIdx.x & 1) == 0);
  const int tid = threadIdx.x;
  const int wv  = tid >> 6;          // 0..3
  const int ln  = tid & 63;
  const int q   = ln >> 4;
  const int n   = ln & 15;
  const int bg0 = b * NB;
  const int u0  = 16*wv + 4*q;
  const int kt_  = u0 >> 5;
  const int q2_  = (u0 >> 3) & 3;
  const int jj0_ = u0 & 7;                          // {0,4}
  const int rdo  = q*FROW + n*8;                    // frag read offset
  const int wro  = q2_*FROW + n*8 + jj0_;           // frag write offset
  const int gwo  = kt_*512 + q2_*128 + n*8 + jj0_;  // hist write offset
  const int ro   = q*128 + n*8;                     // hist read offset

  short* __restrict__ hoffb = hoff + (size_t)b * (4*FBLK);   // 2176 shorts
  float* __restrict__ cgb   = cg + (size_t)b * 1024;          // 64x16 f32
  uint32_t* flagA  = flags + (size_t)b * 64;
  uint32_t* flagFC = flags + (size_t)b * 64 + 32;
  short* hb = nullptr;                                        // per-sweep hist base

  if (isA){
    // =================== A-block: LSTM1 producer (4 waves) ===================
    for (int i = tid; i < WIN*NB; i += 256){ int t = i >> 4, bb = i & 15; win_s[t][bb] = x[(bg0 + bb)*169 + t]; }

    bf16x8 A1hi[4][2], A1lo[4][2], Ain1[4];
    f32x4 b1c[4];
    #pragma unroll
    for (int e = 0; e < 4; e++){
      const int ja = 64*e + 16*wv + n;
      #pragma unroll
      for (int kt = 0; kt < 2; kt++){
        const float* pw = Whh1 + ja*64 + kt*32 + q*8;
        #pragma unroll
        for (int jj = 0; jj < 8; jj++){ short h,l; split_s(pw[jj], h, l); A1hi[e][kt][jj] = h; A1lo[e][kt][jj] = l; }
      }
      bf16x8 ain = {0,0,0,0,0,0,0,0};
      if (q == 0){ short wh, wl; split_s(Wih1[ja], wh, wl); ain[0] = wh; ain[1] = wh; ain[2] = wl; }
      Ain1[e] = ain;
      const int jc = 64*e + u0;
      #pragma unroll
      for (int r = 0; r < 4; r++) b1c[e][r] = bih1[jc+r] + bhh1[jc+r];
    }
    float c1[4];

    // rb/wb/first/fin compile-time at every call site. xv passed in.
    auto lstm1 = [&](int rb, int wb, float xv, int t, bool first, bool fin){
      f32x4 acc[4];
      bf16x8 bin = {0,0,0,0,0,0,0,0};
      { uint32_t xp = cvtpk2(xv, xv);
        float rx = xv - hi_even(xp);
        uint32_t xq = cvtpk2(rx, rx);
        if (q == 0){ bin[0] = (short)xp; bin[1] = (short)xq; bin[2] = (short)xp; } }
      if (first){
        #pragma unroll
        for (int e = 0; e < 4; e++) acc[e] = mfma16(Ain1[e], bin, b1c[e]);
      } else {
        bf16x8 Bh0 = *(const bf16x8*)&aS[FB(rb,0,0)+rdo];
        bf16x8 Bl0 = *(const bf16x8*)&aS[FB(rb,1,0)+rdo];
        bf16x8 Bh1 = *(const bf16x8*)&aS[FB(rb,0,1)+rdo];
        bf16x8 Bl1 = *(const bf16x8*)&aS[FB(rb,1,1)+rdo];
        #pragma unroll
        for (int e = 0; e < 4; e++){
          f32x4 a = b1c[e];
          a = mfma16(A1hi[e][0], Bh0, a);
          a = mfma16(A1hi[e][0], Bl0, a);
          a = mfma16(A1lo[e][0], Bh0, a);
          a = mfma16(A1hi[e][1], Bh1, a);
          a = mfma16(A1hi[e][1], Bl1, a);
          a = mfma16(A1lo[e][1], Bh1, a);
          a = mfma16(Ain1[e], bin, a);
          acc[e] = a;
        }
      }
      float hn[4];
      lstm_epi(acc, c1, hn);
      uint32_t p01 = cvtpk2(hn[0], hn[1]);
      uint32_t p23 = cvtpk2(hn[2], hn[3]);
      f32x2 r01 = (f32x2){hn[0], hn[1]} - (f32x2){hi_even(p01), hi_odd(p01)};
      f32x2 r23 = (f32x2){hn[2], hn[3]} - (f32x2){hi_even(p23), hi_odd(p23)};
      uint32_t q01 = cvtpk2(r01.x, r01.y);
      uint32_t q23 = cvtpk2(r23.x, r23.y);
      *(uint2*)&aS[FB(wb,0,kt_)+wro] = make_uint2(p01, p23);
      *(uint2*)&aS[FB(wb,1,kt_)+wro] = make_uint2(q01, q23);
      uint32_t m01 = (hn[0] > 0.0f ? 0x0000FFFFu : 0u) | (hn[1] > 0.0f ? 0xFFFF0000u : 0u);
      uint32_t m23 = (hn[2] > 0.0f ? 0x0000FFFFu : 0u) | (hn[3] > 0.0f ? 0xFFFF0000u : 0u);
      short* Hp = hb + (size_t)t * 2048;
      *(uint2*)&Hp[gwo]        = make_uint2(p01 & m01, p23 & m23);
      *(uint2*)&Hp[1024 + gwo] = make_uint2(q01 & m01, q23 & m23);
      if (fin){
        // h1-final (non-relu) handoff -> global, mirror of aS frag layout
        *(uint2*)&hoffb[FB(0,0,kt_)+wro] = make_uint2(p01, p23);
        *(uint2*)&hoffb[FB(0,1,kt_)+wro] = make_uint2(q01, q23);
      }
    };

    auto getx = [&](int sg, int t)->float{
      int s = sg + t;
      if (s < WIN) return win_s[s][n];
      return out[(bg0 + n)*24 + (s - WIN)];    // FC(s-WIN), fenced by flagFC
    };

    for (int sg = 0; sg < NSTEPS; sg++){
      hb = hist + ((size_t)((sg & 1)*NBLK + b)) * WIN * 2048;
      #pragma unroll
      for (int r = 0; r < 4; r++) c1[r] = 0.0f;
      __syncthreads();
      lstm1(0, 1, getx(sg, 0), 0, true, false);
      for (int t = 1; t < WIN-1; t += 2){
        __syncthreads();
        lstm1(1, 0, getx(sg, t), t, false, false);
        __syncthreads();
        lstm1(0, 1, getx(sg, t+1), t+1, false, false);
      }
      // t=167 consumes FC(sg-1) -> poll (j < sg-1 were fenced in earlier sweeps)
      if (sg >= 1){
        if (tid == 0) flag_wait(&flagFC[sg-1]);
        __syncthreads();
        __threadfence();                         // acquire for all waves
      }
      __syncthreads();
      lstm1(1, 0, getx(sg, WIN-1), WIN-1, false, true);
      #pragma unroll
      for (int r = 0; r < 4; r++) cgb[(u0 + r)*16 + n] = c1[r];
      __syncthreads();                           // drains all waves' vmcnt
      if (tid == 0) flag_set(&flagA[sg]);
    }

  } else {
    // =================== B-block: LSTM2 consumer + FC (4 waves) ===================
    for (int i = tid; i < 64*65; i += 256){ int j = i / 65, k = i % 65; fc1w_s[j*68 + k] = fc1w[i]; }
    if (tid < NB) dval_s[tid] = x[(bg0 + tid)*169 + 168];

    const float fc1b_r = fc1b[ln];
    const float fc2w_r = fc2w[ln];
    const float fc2b_r = fc2b[0];

    bf16x8 A2hi[4][4], A2lo[4][4];
    f32x4 b2c[4];
    #pragma unroll
    for (int e = 0; e < 4; e++){
      const int ja = 64*e + 16*wv + n;
      #pragma unroll
      for (int kt = 0; kt < 4; kt++){
        const float* pw = (kt < 2 ? (Wih2 + ja*64 + kt*32) : (Whh2 + ja*64 + (kt-2)*32)) + q*8;
        #pragma unroll
        for (int jj = 0; jj < 8; jj++){ short h,l; split_s(pw[jj], h, l); A2hi[e][kt][jj] = h; A2lo[e][kt][jj] = l; }
      }
      const int jc = 64*e + u0;
      #pragma unroll
      for (int r = 0; r < 4; r++) b2c[e][r] = bih2[jc+r] + bhh2[jc+r];
    }
    float c2[4];
    bf16x8 ch0, cl0, ch1, cl1, nh0, nl0, nh1, nl1;

    auto loadc = [&](int t){
      const short* Hp = hb + (size_t)t * 2048;
      ch0 = *(const bf16x8*)&Hp[ro];
      cl0 = *(const bf16x8*)&Hp[1024 + ro];
      ch1 = *(const bf16x8*)&Hp[512 + ro];
      cl1 = *(const bf16x8*)&Hp[1536 + ro];
    };
    auto loadn = [&](int t){
      const short* Hp = hb + (size_t)t * 2048;
      nh0 = *(const bf16x8*)&Hp[ro];
      nl0 = *(const bf16x8*)&Hp[1024 + ro];
      nh1 = *(const bf16x8*)&Hp[512 + ro];
      nl1 = *(const bf16x8*)&Hp[1536 + ro];
    };
    auto shift = [&](){ ch0 = nh0; cl0 = nl0; ch1 = nh1; cl1 = nl1; };

    auto lstm2 = [&](const short* Sr, int rb, short* Sw, int wb, bool last){
      bf16x8 L2h0 = *(const bf16x8*)&Sr[FB(rb,0,0)+rdo];
      bf16x8 L2l0 = *(const bf16x8*)&Sr[FB(rb,1,0)+rdo];
      bf16x8 L2h1 = *(const bf16x8*)&Sr[FB(rb,0,1)+rdo];
      bf16x8 L2l1 = *(const bf16x8*)&Sr[FB(rb,1,1)+rdo];
      f32x4 acc[4];
      #pragma unroll
      for (int e = 0; e < 4; e++){
        f32x4 a = b2c[e];
        a = mfma16(A2hi[e][0], ch0, a);
        a = mfma16(A2hi[e][0], cl0, a);
        a = mfma16(A2lo[e][0], ch0, a);
        a = mfma16(A2hi[e][1], ch1, a);
        a = mfma16(A2hi[e][1], cl1, a);
        a = mfma16(A2lo[e][1], ch1, a);
        a = mfma16(A2hi[e][2], L2h0, a);
        a = mfma16(A2hi[e][2], L2l0, a);
        a = mfma16(A2lo[e][2], L2h0, a);
        a = mfma16(A2hi[e][3], L2h1, a);
        a = mfma16(A2hi[e][3], L2l1, a);
        a = mfma16(A2lo[e][3], L2h1, a);
        acc[e] = a;
      }
      float hn[4];
      lstm_epi(acc, c2, hn);
      if (!last){
        uint32_t p01 = cvtpk2(hn[0], hn[1]);
        uint32_t p23 = cvtpk2(hn[2], hn[3]);
        f32x2 r01 = (f32x2){hn[0], hn[1]} - (f32x2){hi_even(p01), hi_odd(p01)};
        f32x2 r23 = (f32x2){hn[2], hn[3]} - (f32x2){hi_even(p23), hi_odd(p23)};
        *(uint2*)&Sw[FB(wb,0,kt_)+wro] = make_uint2(p01, p23);
        *(uint2*)&Sw[FB(wb,1,kt_)+wro] = make_uint2(cvtpk2(r01.x, r01.y), cvtpk2(r23.x, r23.y));
      } else {
        #pragma unroll
        for (int r = 0; r < 4; r++) Hlast[n][u0 + r] = fmaxf(hn[r], 0.0f);
      }
    };

    auto fc_head = [&](int s){
      float o4[4];
      #pragma unroll
      for (int bi = 0; bi < 4; bi++){
        const int b4 = 4*wv + bi;
        float a1 = fc1b_r;
        #pragma unroll
        for (int k4 = 0; k4 < 16; k4++){
          const float* wp = &fc1w_s[ln*68 + k4*4];
          const float* hp = &Hlast[b4][k4*4];
          a1 += wp[0]*hp[0] + wp[1]*hp[1] + wp[2]*hp[2] + wp[3]*hp[3];
        }
        a1 += dval_s[b4] * fc1w_s[ln*68 + 64];
        float v = a1 * fc2w_r;
        #pragma unroll
        for (int off = 32; off > 0; off >>= 1) v += __shfl_xor(v, off);
        o4[bi] = v + fc2b_r;
      }
      if (ln == 0){
        #pragma unroll
        for (int bi = 0; bi < 4; bi++){
          const int b4 = 4*wv + bi;
          out[(bg0 + b4)*24 + s] = o4[bi];
        }
      }
    };

    for (int sg = 0; sg < NSTEPS; sg++){
      if (tid == 0) flag_wait(&flagA[sg]);
      __syncthreads();
      __threadfence();                           // acquire: invalidate stale hist lines
      hb = hist + ((size_t)((sg & 1)*NBLK + b)) * WIN * 2048;
      #pragma unroll
      for (int r = 0; r < 4; r++) c2[r] = cgb[(u0 + r)*16 + n];
      loadc(0);
      loadn(1);
      lstm2(hoffb, 0, bS, 1, false);             // t=0: h2-init = h1-final (global frag)
      shift();
      for (int t = 1; t < WIN-1; t += 2){
        __syncthreads();
        loadn(t + 1);
        lstm2(bS, 1, bS, 0, false);              // odd t
        shift();
        __syncthreads();
        loadn(t + 2);                            // t+2 <= 167
        lstm2(bS, 0, bS, 1, false);              // even t+1
        shift();
      }
      __syncthreads();
      lstm2(bS, 1, bS, 0, true);                 // t=167 -> Hlast
      __syncthreads();
      fc_head(sg);
      __syncthreads();                           // drains out[] stores (vmcnt)
      if (tid == 0) flag_set(&flagFC[sg]);
    }
  }
}

// ============================================================================
// R17 fused kernel (proven 4704 us): used when workspace fits single hist only.
// ============================================================================
__global__ __launch_bounds__(NT, 2) void lstm_fused_kernel(
  const float* __restrict__ x,    const float* __restrict__ Wih1, const float* __restrict__ Whh1,
  const float* __restrict__ bih1, const float* __restrict__ bhh1,
  const float* __restrict__ Wih2, const float* __restrict__ Whh2,
  const float* __restrict__ bih2, const float* __restrict__ bhh2,
  const float* __restrict__ fc1w, const float* __restrict__ fc1b,
  const float* __restrict__ fc2w, const float* __restrict__ fc2b,
  float* __restrict__ out, short* __restrict__ hist)
{
  __shared__ __align__(16) short aS[2*2*2*FBLK];
  __shared__ __align__(16) short bS[2*2*2*FBLK];
  __shared__ float cS[64][16];
  __shared__ float win_s[WIN][NB];
  __shared__ float Hlast[NB][68];
  __shared__ float fc1w_s[64*68];
  __shared__ float dval_s[NB];

  const int tid = threadIdx.x;
  const int wv8 = tid >> 6;
  const int wv  = wv8 & 3;
  const bool isA = (wv8 < 4);
  const int ln  = tid & 63;
  const int q   = ln >> 4;
  const int n   = ln & 15;
  const int bg0 = blockIdx.x * NB;
  const int u0  = 16*wv + 4*q;
  const int kt_  = u0 >> 5;
  const int q2_  = (u0 >> 3) & 3;
  const int jj0_ = u0 & 7;
  const int rdo  = q*FROW + n*8;
  const int wro  = q2_*FROW + n*8 + jj0_;
  const int gwo  = kt_*512 + q2_*128 + n*8 + jj0_;
  const int ro   = q*128 + n*8;
  short* __restrict__ hblk = hist + (size_t)blockIdx.x * WIN * 2048;

  for (int i = tid; i < WIN*NB; i += NT){ int t = i >> 4, b = i & 15; win_s[t][b] = x[(bg0 + b)*169 + t]; }
  for (int i = tid; i < 64*65; i += NT){ int j = i / 65, k = i % 65; fc1w_s[j*68 + k] = fc1w[i]; }
  if (tid < NB) dval_s[tid] = x[(bg0 + tid)*169 + 168];

  const float fc1b_r = fc1b[ln];
  const float fc2w_r = fc2w[ln];
  const float fc2b_r = fc2b[0];

  auto fc_head = [&](int s){
    float o2[2];
    #pragma unroll
    for (int bi = 0; bi < 2; bi++){
      const int b = 2*wv8 + bi;
      float a1 = fc1b_r;
      #pragma unroll
      for (int k4 = 0; k4 < 16; k4++){
        const float* wp = &fc1w_s[ln*68 + k4*4];
        const float* hp = &Hlast[b][k4*4];
        a1 += wp[0]*hp[0] + wp[1]*hp[1] + wp[2]*hp[2] + wp[3]*hp[3];
      }
      a1 += dval_s[b] * fc1w_s[ln*68 + 64];
      float v = a1 * fc2w_r;
      #pragma unroll
      for (int off = 32; off > 0; off >>= 1) v += __shfl_xor(v, off);
      o2[bi] = v + fc2b_r;
    }
    if (ln == 0){
      #pragma unroll
      for (int bi = 0; bi < 2; bi++){
        const int b = 2*wv8 + bi;
        out[(bg0 + b)*24 + s] = o2[bi];
        win_s[s % WIN][b] = o2[bi];
      }
    }
  };

  if (isA){
    bf16x8 A1hi[4][2], A1lo[4][2], Ain1[4];
    f32x4 b1c[4];
    #pragma unroll
    for (int e = 0; e < 4; e++){
      const int ja = 64*e + 16*wv + n;
      #pragma unroll
      for (int kt = 0; kt < 2; kt++){
        const float* pw = Whh1 + ja*64 + kt*32 + q*8;
        #pragma unroll
        for (int jj = 0; jj < 8; jj++){ short h,l; split_s(pw[jj], h, l); A1hi[e][kt][jj] = h; A1lo[e][kt][jj] = l; }
      }
      bf16x8 ain = {0,0,0,0,0,0,0,0};
      if (q == 0){ short wh, wl; split_s(Wih1[ja], wh, wl); ain[0] = wh; ain[1] = wh; ain[2] = wl; }
      Ain1[e] = ain;
      const int jc = 64*e + u0;
      #pragma unroll
      for (int r = 0; r < 4; r++) b1c[e][r] = bih1[jc+r] + bhh1[jc+r];
    }
    float c1[4];

    auto lstm1 = [&](int rb, int wb, int slot, int t, bool first){
      f32x4 acc[4];
      bf16x8 bin = {0,0,0,0,0,0,0,0};
      { float xv = win_s[slot][n];
        uint32_t xp = cvtpk2(xv, xv);
        float rx = xv - hi_even(xp);
        uint32_t xq = cvtpk2(rx, rx);
        if (q == 0){ bin[0] = (short)xp; bin[1] = (short)xq; bin[2] = (short)xp; } }
      if (first){
        #pragma unroll
        for (int e = 0; e < 4; e++) acc[e] = mfma16(Ain1[e], bin, b1c[e]);
      } else {
        bf16x8 Bh0 = *(const bf16x8*)&aS[FB(rb,0,0)+rdo];
        bf16x8 Bl0 = *(const bf16x8*)&aS[FB(rb,1,0)+rdo];
        bf16x8 Bh1 = *(const bf16x8*)&aS[FB(rb,0,1)+rdo];
        bf16x8 Bl1 = *(const bf16x8*)&aS[FB(rb,1,1)+rdo];
        #pragma unroll
        for (int e = 0; e < 4; e++){
          f32x4 a = b1c[e];
          a = mfma16(A1hi[e][0], Bh0, a);
          a = mfma16(A1hi[e][0], Bl0, a);
          a = mfma16(A1lo[e][0], Bh0, a);
          a = mfma16(A1hi[e][1], Bh1, a);
          a = mfma16(A1hi[e][1], Bl1, a);
          a = mfma16(A1lo[e][1], Bh1, a);
          a = mfma16(Ain1[e], bin, a);
          acc[e] = a;
        }
      }
      float hn[4];
      lstm_epi(acc, c1, hn);
      uint32_t p01 = cvtpk2(hn[0], hn[1]);
      uint32_t p23 = cvtpk2(hn[2], hn[3]);
      f32x2 r01 = (f32x2){hn[0], hn[1]} - (f32x2){hi_even(p01), hi_odd(p01)};
      f32x2 r23 = (f32x2){hn[2], hn[3]} - (f32x2){hi_even(p23), hi_odd(p23)};
      uint32_t q01 = cvtpk2(r01.x, r01.y);
      uint32_t q23 = cvtpk2(r23.x, r23.y);
      *(uint2*)&aS[FB(wb,0,kt_)+wro] = make_uint2(p01, p23);
      *(uint2*)&aS[FB(wb,1,kt_)+wro] = make_uint2(q01, q23);
      uint32_t m01 = (hn[0] > 0.0f ? 0x0000FFFFu : 0u) | (hn[1] > 0.0f ? 0xFFFF0000u : 0u);
      uint32_t m23 = (hn[2] > 0.0f ? 0x0000FFFFu : 0u) | (hn[3] > 0.0f ? 0xFFFF0000u : 0u);
      short* Hp = hblk + (size_t)t * 2048;
      *(uint2*)&Hp[gwo]        = make_uint2(p01 & m01, p23 & m23);
      *(uint2*)&Hp[1024 + gwo] = make_uint2(q01 & m01, q23 & m23);
    };

    #pragma unroll
    for (int r = 0; r < 4; r++) c1[r] = 0.0f;
    __syncthreads();
    lstm1(0, 1, 0, 0, true);
    for (int t = 1; t < WIN-1; t += 2){
      __syncthreads();
      lstm1(1, 0, t, t, false);
      __syncthreads();
      lstm1(0, 1, t+1, t+1, false);
    }
    __syncthreads();
    lstm1(1, 0, WIN-1, WIN-1, false);
    #pragma unroll
    for (int r = 0; r < 4; r++) cS[u0 + r][n] = c1[r];

    for (int sg = 1; sg < NSTEPS; sg++){
      #pragma unroll
      for (int r = 0; r < 4; r++) c1[r] = 0.0f;
      int slot = sg;
      __syncthreads();
      lstm1(0, 1, slot, 0, true);
      slot++;
      for (int t = 1; t < WIN-1; t += 2){
        __syncthreads();
        lstm1(1, 0, slot, t, false);
        slot++; if (slot == WIN) slot = 0;
        __syncthreads();
        lstm1(0, 1, slot, t+1, false);
        slot++; if (slot == WIN) slot = 0;
      }
      __syncthreads();
      __syncthreads();
      fc_head(sg - 1);
      __syncthreads();
      lstm1(1, 0, slot, WIN-1, false);
      #pragma unroll
      for (int r = 0; r < 4; r++) cS[u0 + r][n] = c1[r];
    }

    for (int i = 0; i < WIN + 1; i++) __syncthreads();
    fc_head(NSTEPS - 1);

  } else {
    bf16x8 A2hi[4][4], A2lo[4][4];
    f32x4 b2c[4];
    #pragma unroll
    for (int e = 0; e < 4; e++){
      const int ja = 64*e + 16*wv + n;
      #pragma unroll
      for (int kt = 0; kt < 4; kt++){
        const float* pw = (kt < 2 ? (Wih2 + ja*64 + kt*32) : (Whh2 + ja*64 + (kt-2)*32)) + q*8;
        #pragma unroll
        for (int jj = 0; jj < 8; jj++){ short h,l; split_s(pw[jj], h, l); A2hi[e][kt][jj] = h; A2lo[e][kt][jj] = l; }
      }
      const int jc = 64*e + u0;
      #pragma unroll
      for (int r = 0; r < 4; r++) b2c[e][r] = bih2[jc+r] + bhh2[jc+r];
    }
    float c2[4];
    bf16x8 ch0, cl0, ch1, cl1, nh0, nl0, nh1, nl1;

    auto loadc = [&](int t){
      const short* Hp = hblk + (size_t)t * 2048;
      ch0 = *(const bf16x8*)&Hp[ro];
      cl0 = *(const bf16x8*)&Hp[1024 + ro];
      ch1 = *(const bf16x8*)&Hp[512 + ro];
      cl1 = *(const bf16x8*)&Hp[1536 + ro];
    };
    auto loadn = [&](int t){
      const short* Hp = hblk + (size_t)t * 2048;
      nh0 = *(const bf16x8*)&Hp[ro];
      nl0 = *(const bf16x8*)&Hp[1024 + ro];
      nh1 = *(const bf16x8*)&Hp[512 + ro];
      nl1 = *(const bf16x8*)&Hp[1536 + ro];
    };
    auto shift = [&](){ ch0 = nh0; cl0 = nl0; ch1 = nh1; cl1 = nl1; };

    auto lstm2 = [&](const short* Sr, int rb, short* Sw, int wb, bool last){
      bf16x8 L2h0 = *(const bf16x8*)&Sr[FB(rb,0,0)+rdo];
      bf16x8 L2l0 = *(const bf16x8*)&Sr[FB(rb,1,0)+rdo];
      bf16x8 L2h1 = *(const bf16x8*)&Sr[FB(rb,0,1)+rdo];
      bf16x8 L2l1 = *(const bf16x8*)&Sr[FB(rb,1,1)+rdo];
      f32x4 acc[4];
      #pragma unroll
      for (int e = 0; e < 4; e++){
        f32x4 a = b2c[e];
        a = mfma16(A2hi[e][0], ch0, a);
        a = mfma16(A2hi[e][0], cl0, a);
        a = mfma16(A2lo[e][0], ch0, a);
        a = mfma16(A2hi[e][1], ch1, a);
        a = mfma16(A2hi[e][1], cl1, a);
        a = mfma16(A2lo[e][1], ch1, a);
        a = mfma16(A2hi[e][2], L2h0, a);
        a = mfma16(A2hi[e][2], L2l0, a);
        a = mfma16(A2lo[e][2], L2h0, a);
        a = mfma16(A2hi[e][3], L2h1, a);
        a = mfma16(A2hi[e][3], L2l1, a);
        a = mfma16(A2lo[e][3], L2h1, a);
        acc[e] = a;
      }
      float hn[4];
      lstm_epi(acc, c2, hn);
      if (!last){
        uint32_t p01 = cvtpk2(hn[0], hn[1]);
        uint32_t p23 = cvtpk2(hn[2], hn[3]);
        f32x2 r01 = (f32x2){hn[0], hn[1]} - (f32x2){hi_even(p01), hi_odd(p01)};
        f32x2 r23 = (f32x2){hn[2], hn[3]} - (f32x2){hi_even(p23), hi_odd(p23)};
        *(uint2*)&Sw[FB(wb,0,kt_)+wro] = make_uint2(p01, p23);
        *(uint2*)&Sw[FB(wb,1,kt_)+wro] = make_uint2(cvtpk2(r01.x, r01.y), cvtpk2(r23.x, r23.y));
      } else {
        #pragma unroll
        for (int r = 0; r < 4; r++) Hlast[n][u0 + r] = fmaxf(hn[r], 0.0f);
      }
    };

    for (int i = 0; i < WIN; i++) __syncthreads();

    for (int sg = 1; sg < NSTEPS; sg++){
      loadc(0);
      loadn(1);
      __syncthreads();
      #pragma unroll
      for (int r = 0; r < 4; r++) c2[r] = cS[u0 + r][n];
      lstm2(aS, 0, bS, 1, false);
      shift();
      for (int t = 1; t < WIN-1; t += 2){
        __syncthreads();
        loadn(t + 1);
        lstm2(bS, 1, bS, 0, false);
        shift();
        __syncthreads();
        loadn(t + 2);
        lstm2(bS, 0, bS, 1, false);
        shift();
      }
      __syncthreads();
      lstm2(bS, 1, bS, 0, true);
      __syncthreads();
      fc_head(sg - 1);
      __syncthreads();
    }

    {
      loadc(0);
      loadn(1);
      __syncthreads();
      #pragma unroll
      for (int r = 0; r < 4; r++) c2[r] = cS[u0 + r][n];
      lstm2(aS, 0, bS, 1, false);
      shift();
      for (int t = 1; t < WIN-1; t += 2){
        __syncthreads();
        loadn(t + 1);
        lstm2(bS, 1, bS, 0, false);
        shift();
        __syncthreads();
        loadn(t + 2);
        lstm2(bS, 0, bS, 1, false);
        shift();
      }
      __syncthreads();
      lstm2(bS, 1, bS, 0, true);
      __syncthreads();
      fc_head(NSTEPS - 1);
    }
  }
}

// ============================================================================
// Fallback (no workspace): replay scheme, 256 threads. Safety only.
// ============================================================================
__global__ __launch_bounds__(256, 1) void lstm_fallback_kernel(
  const float* __restrict__ x,    const float* __restrict__ Wih1, const float* __restrict__ Whh1,
  const float* __restrict__ bih1, const float* __restrict__ bhh1,
  const float* __restrict__ Wih2, const float* __restrict__ Whh2,
  const float* __restrict__ bih2, const float* __restrict__ bhh2,
  const float* __restrict__ fc1w, const float* __restrict__ fc1b,
  const float* __restrict__ fc2w, const float* __restrict__ fc2b,
  float* __restrict__ out)
{
  __shared__ __align__(16) short aS[2*2*2*FBLK];
  __shared__ __align__(16) short r1f[2*2*2*FBLK];
  __shared__ __align__(16) short rlf[2*2*2*FBLK];
  __shared__ float win_s[WIN][NB];
  __shared__ float Hlast[NB][68];
  __shared__ float fc1w_s[64*68];
  __shared__ float dval_s[NB];

  const int tid = threadIdx.x;
  const int wv  = tid >> 6;
  const int ln  = tid & 63;
  const int q   = ln >> 4;
  const int n   = ln & 15;
  const int bg0 = blockIdx.x * NB;
  const int u0  = 16*wv + 4*q;
  const int kt_  = u0 >> 5;
  const int q2_  = (u0 >> 3) & 3;
  const int jj0_ = u0 & 7;
  const int rdo  = q*FROW + n*8;
  const int wro  = q2_*FROW + n*8 + jj0_;

  for (int i = tid; i < WIN*NB; i += 256){ int t = i >> 4, b = i & 15; win_s[t][b] = x[(bg0 + b)*169 + t]; }
  for (int i = tid; i < 64*65; i += 256){ int j = i / 65, k = i % 65; fc1w_s[j*68 + k] = fc1w[i]; }
  if (tid < NB) dval_s[tid] = x[(bg0 + tid)*169 + 168];

  const float fc1b_r = fc1b[ln];
  const float fc2w_r = fc2w[ln];
  const float fc2b_r = fc2b[0];

  bf16x8 A1hi[4][2], A1lo[4][2], Ain1[4];
  bf16x8 A2hi[4][4], A2lo[4][4];
  f32x4 b1c[4], b2c[4];
  #pragma unroll
  for (int e = 0; e < 4; e++){
    const int ja = 64*e + 16*wv + n;
    #pragma unroll
    for (int kt = 0; kt < 2; kt++){
      const float* pw = Whh1 + ja*64 + kt*32 + q*8;
      #pragma unroll
      for (int jj = 0; jj < 8; jj++){ short h,l; split_s(pw[jj], h, l); A1hi[e][kt][jj] = h; A1lo[e][kt][jj] = l; }
    }
    #pragma unroll
    for (int kt = 0; kt < 4; kt++){
      const float* pw = (kt < 2 ? (Wih2 + ja*64 + kt*32) : (Whh2 + ja*64 + (kt-2)*32)) + q*8;
      #pragma unroll
      for (int jj = 0; jj < 8; jj++){ short h,l; split_s(pw[jj], h, l); A2hi[e][kt][jj] = h; A2lo[e][kt][jj] = l; }
    }
    bf16x8 ain = {0,0,0,0,0,0,0,0};
    if (q == 0){ short wh, wl; split_s(Wih1[ja], wh, wl); ain[0] = wh; ain[1] = wh; ain[2] = wl; }
    Ain1[e] = ain;
    const int jc = 64*e + u0;
    #pragma unroll
    for (int r = 0; r < 4; r++){
      b1c[e][r] = bih1[jc+r] + bhh1[jc+r];
      b2c[e][r] = bih2[jc+r] + bhh2[jc+r];
    }
  }

  float c1[4], c2[4], c1r[4];

  auto lstm1_step = [&](short* S, float* cst, int rb, int wb, int slot, bool relu_out){
    bf16x8 Bh0 = *(const bf16x8*)&S[FB(rb,0,0)+rdo];
    bf16x8 Bl0 = *(const bf16x8*)&S[FB(rb,1,0)+rdo];
    bf16x8 Bh1 = *(const bf16x8*)&S[FB(rb,0,1)+rdo];
    bf16x8 Bl1 = *(const bf16x8*)&S[FB(rb,1,1)+rdo];
    bf16x8 bin = {0,0,0,0,0,0,0,0};
    { float xv = win_s[slot][n]; uint32_t xh, xl; split_t(xv, xh, xl);
      if (q == 0){ bin[0] = (short)xh; bin[1] = (short)xl; bin[2] = (short)xh; } }
    f32x4 acc[4];
    #pragma unroll
    for (int e = 0; e < 4; e++){
      f32x4 a = b1c[e];
      a = mfma16(A1hi[e][0], Bh0, a);
      a = mfma16(A1hi[e][0], Bl0, a);
      a = mfma16(A1lo[e][0], Bh0, a);
      a = mfma16(A1hi[e][1], Bh1, a);
      a = mfma16(A1hi[e][1], Bl1, a);
      a = mfma16(A1lo[e][1], Bh1, a);
      a = mfma16(Ain1[e], bin, a);
      acc[e] = a;
    }
    float hn[4];
    #pragma unroll
    for (int r = 0; r < 4; r++){
      float cn = __builtin_fmaf(sigm(acc[1][r]), cst[r], sigtanh(acc[0][r], acc[2][r]));
      cst[r] = cn;
      hn[r] = sigtanh(acc[3][r], cn);
    }
    uint32_t ph[4], pl[4];
    #pragma unroll
    for (int r = 0; r < 4; r++) split_t(hn[r], ph[r], pl[r]);
    *(uint2*)&S[FB(wb,0,kt_)+wro] = make_uint2(ph[0] | (ph[1]<<16), ph[2] | (ph[3]<<16));
    *(uint2*)&S[FB(wb,1,kt_)+wro] = make_uint2(pl[0] | (pl[1]<<16), pl[2] | (pl[3]<<16));
    if (relu_out){
      uint32_t sh[4], sl[4];
      #pragma unroll
      for (int r = 0; r < 4; r++){ bool pos = hn[r] > 0.0f; sh[r] = pos ? ph[r] : 0u; sl[r] = pos ? pl[r] : 0u; }
      *(uint2*)&rlf[FB(rb,0,kt_)+wro] = make_uint2(sh[0] | (sh[1]<<16), sh[2] | (sh[3]<<16));
      *(uint2*)&rlf[FB(rb,1,kt_)+wro] = make_uint2(sl[0] | (sl[1]<<16), sl[2] | (sl[3]<<16));
    }
  };

  auto lstm2_core = [&](bf16x8 L1h0, bf16x8 L1l0, bf16x8 L1h1, bf16x8 L1l1,
                        int rbuf, int wbuf, bool last){
    bf16x8 L2h0 = *(const bf16x8*)&aS[FB(rbuf,0,0)+rdo];
    bf16x8 L2l0 = *(const bf16x8*)&aS[FB(rbuf,1,0)+rdo];
    bf16x8 L2h1 = *(const bf16x8*)&aS[FB(rbuf,0,1)+rdo];
    bf16x8 L2l1 = *(const bf16x8*)&aS[FB(rbuf,1,1)+rdo];
    f32x4 acc[4];
    #pragma unroll
    for (int e = 0; e < 4; e++){
      f32x4 a = b2c[e];
      a = mfma16(A2hi[e][0], L1h0, a);
      a = mfma16(A2hi[e][0], L1l0, a);
      a = mfma16(A2lo[e][0], L1h0, a);
      a = mfma16(A2hi[e][1], L1h1, a);
      a = mfma16(A2hi[e][1], L1l1, a);
      a = mfma16(A2lo[e][1], L1h1, a);
      a = mfma16(A2hi[e][2], L2h0, a);
      a = mfma16(A2hi[e][2], L2l0, a);
      a = mfma16(A2lo[e][2], L2h0, a);
      a = mfma16(A2hi[e][3], L2h1, a);
      a = mfma16(A2hi[e][3], L2l1, a);
      a = mfma16(A2lo[e][3], L2h1, a);
      acc[e] = a;
    }
    float hn[4];
    #pragma unroll
    for (int r = 0; r < 4; r++){
      float cn = __builtin_fmaf(sigm(acc[1][r]), c2[r], sigtanh(acc[0][r], acc[2][r]));
      c2[r] = cn;
      hn[r] = sigtanh(acc[3][r], cn);
    }
    if (!last){
      uint32_t ph[4], pl[4];
      #pragma unroll
      for (int r = 0; r < 4; r++) split_t(hn[r], ph[r], pl[r]);
      *(uint2*)&aS[FB(wbuf,0,kt_)+wro] = make_uint2(ph[0] | (ph[1]<<16), ph[2] | (ph[3]<<16));
      *(uint2*)&aS[FB(wbuf,1,kt_)+wro] = make_uint2(pl[0] | (pl[1]<<16), pl[2] | (pl[3]<<16));
    } else {
      #pragma unroll
      for (int r = 0; r < 4; r++) Hlast[n][u0 + r] = fmaxf(hn[r], 0.0f);
    }
  };

  for (int s = 0; s < NSTEPS; s++){
    { int* p = (int*)&aS[0];
      for (int i = tid; i < BUF_INTS; i += 256) p[i] = 0; }
    #pragma unroll
    for (int r = 0; r < 4; r++) c1[r] = 0.0f;
    int slot = s;
    for (int t = 0; t < WIN; t++){
      __syncthreads();
      lstm1_step(aS, c1, t & 1, (t & 1) ^ 1, slot, false);
      slot++; if (slot == WIN) slot = 0;
    }
    #pragma unroll
    for (int r = 0; r < 4; r++){ c2[r] = c1[r]; c1r[r] = 0.0f; }
    { int* p = (int*)&r1f[0];
      for (int i = tid; i < BUF_INTS; i += 256) p[i] = 0; }
    slot = s;
    __syncthreads();
    lstm1_step(r1f, c1r, 0, 1, slot, true);
    slot++;
    for (int i = 1; i < WIN; i++){
      __syncthreads();
      const int rb = i & 1, wb = rb ^ 1;
      lstm1_step(r1f, c1r, rb, wb, slot, true);
      bf16x8 L1h0 = *(const bf16x8*)&rlf[FB(wb,0,0)+rdo];
      bf16x8 L1l0 = *(const bf16x8*)&rlf[FB(wb,1,0)+rdo];
      bf16x8 L1h1 = *(const bf16x8*)&rlf[FB(wb,0,1)+rdo];
      bf16x8 L1l1 = *(const bf16x8*)&rlf[FB(wb,1,1)+rdo];
      lstm2_core(L1h0, L1l0, L1h1, L1l1, wb, rb, false);
      slot++; if (slot == WIN) slot = 0;
    }
    __syncthreads();
    {
      const int rb = (WIN - 1) & 1;
      bf16x8 L1h0 = *(const bf16x8*)&rlf[FB(rb,0,0)+rdo];
      bf16x8 L1l0 = *(const bf16x8*)&rlf[FB(rb,1,0)+rdo];
      bf16x8 L1h1 = *(const bf16x8*)&rlf[FB(rb,0,1)+rdo];
      bf16x8 L1l1 = *(const bf16x8*)&rlf[FB(rb,1,1)+rdo];
      lstm2_core(L1h0, L1l0, L1h1, L1l1, rb, 0, true);
    }
    __syncthreads();
    {
      float o4[4];
      #pragma unroll
      for (int bi = 0; bi < 4; bi++){
        const int b = 4*wv + bi;
        float a1 = fc1b_r;
        #pragma unroll
        for (int k4 = 0; k4 < 16; k4++){
          const float* wp = &fc1w_s[ln*68 + k4*4];
          const float* hp = &Hlast[b][k4*4];
          a1 += wp[0]*hp[0] + wp[1]*hp[1] + wp[2]*hp[2] + wp[3]*hp[3];
        }
        a1 += dval_s[b] * fc1w_s[ln*68 + 64];
        float v = a1 * fc2w_r;
        #pragma unroll
        for (int off = 32; off > 0; off >>= 1) v += __shfl_xor(v, off);
        o4[bi] = v + fc2b_r;
      }
      if (ln == 0){
        #pragma unroll
        for (int bi = 0; bi < 4; bi++){
          const int b = 4*wv + bi;
          out[(bg0 + b)*24 + s] = o4[bi];
          win_s[s % WIN][b] = o4[bi];
        }
      }
    }
  }
}

extern "C" void kernel_launch(void* const* d_in, const int* in_sizes, int n_in,
                              void* d_out, int out_size, void* d_ws, size_t ws_size,
                              hipStream_t stream) {
  (void)in_sizes; (void)n_in; (void)out_size;
  const size_t histB = (size_t)2 * NBLK * WIN * 2048 * sizeof(short);   // 336 MB (2-sweep dbuf)
  const size_t hoffB = (size_t)NBLK * 4 * FBLK * sizeof(short);         // h1-final frags
  const size_t cgB   = (size_t)NBLK * 1024 * sizeof(float);             // c1-final
  const size_t flagB = (size_t)NBLK * 64 * sizeof(uint32_t);            // flags
  const size_t needP = histB + hoffB + cgB + flagB;
  const size_t needF = (size_t)NBLK * WIN * 2048 * sizeof(short);       // ~176 MB

  if (ws_size >= needP){
    short* hist = (short*)d_ws;
    short* hoff = (short*)((char*)d_ws + histB);
    float* cg   = (float*)((char*)d_ws + histB + hoffB);
    uint32_t* flags = (uint32_t*)((char*)d_ws + histB + hoffB + cgB);
    const int nflags = NBLK * 64;
    flags_zero_kernel<<<dim3((nflags + 255)/256), dim3(256), 0, stream>>>(flags, nflags);
    lstm_pipe_kernel<<<dim3(2*NBLK), dim3(256), 0, stream>>>(
        (const float*)d_in[0], (const float*)d_in[1], (const float*)d_in[2],
        (const float*)d_in[3], (const float*)d_in[4], (const float*)d_in[5],
        (const float*)d_in[6], (const float*)d_in[7], (const float*)d_in[8],
        (const float*)d_in[9], (const float*)d_in[10], (const float*)d_in[11],
        (const float*)d_in[12], (float*)d_out, hist, hoff, cg, flags);
  } else if (ws_size >= needF){
    lstm_fused_kernel<<<dim3(NBLK), dim3(NT), 0, stream>>>(
        (const float*)d_in[0], (const float*)d_in[1], (const float*)d_in[2],
        (const float*)d_in[3], (const float*)d_in[4], (const float*)d_in[5],
        (const float*)d_in[6], (const float*)d_in[7], (const float*)d_in[8],
        (const float*)d_in[9], (const float*)d_in[10], (const float*)d_in[11],
        (const float*)d_in[12], (float*)d_out, (short*)d_ws);
  } else {
    lstm_fallback_kernel<<<dim3(NBLK), dim3(256), 0, stream>>>(
        (const float*)d_in[0], (const float*)d_in[1], (const float*)d_in[2],
        (const float*)d_in[3], (const float*)d_in[4], (const float*)d_in[5],
        (const float*)d_in[6], (const float*)d_in[7], (const float*)d_in[8],
        (const float*)d_in[9], (const float*)d_in[10], (const float*)d_in[11],
        (const float*)d_in[12], (float*)d_out);
  }
}